// Round 3
// baseline (344.741 us; speedup 1.0000x reference)
//
#include <hip/hip_runtime.h>

#define N_NODES 50000
#define N_EDGES 800000
#define E_TOT   (N_EDGES + N_NODES)   // 850000 (self-loops appended)
#define D_IN    128
#define D_HID   64

#define SCAN_B        256
#define N_SCAN_BLOCKS ((N_NODES + SCAN_B - 1) / SCAN_B)   // 196

// ---------------- graph build ----------------

__global__ __launch_bounds__(256) void k_count(const int* __restrict__ dst,
                                               unsigned* __restrict__ cnt) {
  int e = blockIdx.x * blockDim.x + threadIdx.x;
  if (e < N_EDGES) atomicAdd(&cnt[dst[e]], 1u);
}

__global__ __launch_bounds__(256) void k_dis(unsigned* __restrict__ cnt,
                                             float* __restrict__ dis) {
  int i = blockIdx.x * blockDim.x + threadIdx.x;
  if (i < N_NODES) {
    unsigned c = cnt[i] + 1u;          // + self-loop
    cnt[i] = c;
    dis[i] = rsqrtf((float)c);
  }
}

__global__ __launch_bounds__(SCAN_B) void k_scan1(const unsigned* __restrict__ cnt,
                                                  unsigned* __restrict__ excl,
                                                  unsigned* __restrict__ bsum) {
  __shared__ unsigned s[SCAN_B];
  int i = blockIdx.x * SCAN_B + threadIdx.x;
  unsigned v = (i < N_NODES) ? cnt[i] : 0u;
  s[threadIdx.x] = v;
  __syncthreads();
  for (int off = 1; off < SCAN_B; off <<= 1) {
    unsigned t = (threadIdx.x >= off) ? s[threadIdx.x - off] : 0u;
    __syncthreads();
    s[threadIdx.x] += t;
    __syncthreads();
  }
  if (i < N_NODES) excl[i] = s[threadIdx.x] - v;
  if (threadIdx.x == SCAN_B - 1) bsum[blockIdx.x] = s[SCAN_B - 1];
}

__global__ __launch_bounds__(SCAN_B) void k_scan2(unsigned* __restrict__ bsum) {
  __shared__ unsigned s[SCAN_B];
  unsigned v = (threadIdx.x < N_SCAN_BLOCKS) ? bsum[threadIdx.x] : 0u;
  s[threadIdx.x] = v;
  __syncthreads();
  for (int off = 1; off < SCAN_B; off <<= 1) {
    unsigned t = (threadIdx.x >= off) ? s[threadIdx.x - off] : 0u;
    __syncthreads();
    s[threadIdx.x] += t;
    __syncthreads();
  }
  if (threadIdx.x < N_SCAN_BLOCKS) bsum[threadIdx.x] = s[threadIdx.x] - v;  // exclusive
}

__global__ __launch_bounds__(256) void k_scan3(unsigned* __restrict__ rowptr,
                                               unsigned* __restrict__ fill,
                                               const unsigned* __restrict__ bsum) {
  int i = blockIdx.x * blockDim.x + threadIdx.x;
  if (i < N_NODES) {
    unsigned r = rowptr[i] + bsum[i / SCAN_B];
    rowptr[i] = r;
    fill[i] = r;
  }
  if (i == 0) rowptr[N_NODES] = E_TOT;
}

__global__ __launch_bounds__(256) void k_fill(const int* __restrict__ esrc_in,
                                              const int* __restrict__ edst_in,
                                              const float* __restrict__ dis,
                                              unsigned* __restrict__ fill,
                                              uint2* __restrict__ csr) {
  int e = blockIdx.x * blockDim.x + threadIdx.x;
  if (e >= E_TOT) return;
  int s, d;
  if (e < N_EDGES) { s = esrc_in[e]; d = edst_in[e]; }
  else             { s = d = e - N_EDGES; }          // self-loops
  float nrm = dis[s] * dis[d];
  unsigned pos = atomicAdd(&fill[d], 1u);
  csr[pos] = make_uint2((unsigned)s, __float_as_uint(nrm));
}

// ---------------- dense transform: Y[N][64] = X[N][DIN] @ W[DIN][64] ----------------
// lane = row, wave = 16-col quarter, 2 rows per lane (128 rows / block).
// W staged in LDS once (all reads are wave-uniform float4 broadcasts, conflict-free).
// X read directly from global as per-lane float4 row chunks; no barriers in main loop.

template <int DIN>
__global__ __launch_bounds__(256) void k_gemm(const float4* __restrict__ X4,
                                              const float* __restrict__ W,
                                              float4* __restrict__ Y4) {
  __shared__ float sW[DIN * 64];
  const int tid = threadIdx.x;
  for (int i = tid; i < DIN * 16; i += 256)
    reinterpret_cast<float4*>(sW)[i] = reinterpret_cast<const float4*>(W)[i];
  __syncthreads();

  const int wave = tid >> 6;               // col quarter: cols wave*16 .. wave*16+15
  const int lane = tid & 63;
  const int c0   = wave * 16;
  const int row0 = blockIdx.x * 128 + lane;      // rows row0, row0+64
  const int row1 = row0 + 64;
  const bool ok0 = row0 < N_NODES, ok1 = row1 < N_NODES;
  if (!ok0) return;                         // row1 > row0; no barriers below

  const float4* xr0 = X4 + (size_t)row0 * (DIN / 4);
  const float4* xr1 = X4 + (size_t)row1 * (DIN / 4);

  float4 a00 = {0,0,0,0}, a01 = {0,0,0,0}, a02 = {0,0,0,0}, a03 = {0,0,0,0};
  float4 a10 = {0,0,0,0}, a11 = {0,0,0,0}, a12 = {0,0,0,0}, a13 = {0,0,0,0};

#pragma unroll 8
  for (int kk = 0; kk < DIN / 4; kk++) {
    float4 xv0 = xr0[kk];
    float4 xv1 = ok1 ? xr1[kk] : make_float4(0.f, 0.f, 0.f, 0.f);
#pragma unroll
    for (int i = 0; i < 4; i++) {
      const int k = 4 * kk + i;
      const float4* wr = reinterpret_cast<const float4*>(&sW[k * 64 + c0]);
      float4 w0 = wr[0], w1 = wr[1], w2 = wr[2], w3 = wr[3];
      float x0 = (&xv0.x)[i], x1 = (&xv1.x)[i];
      a00.x += x0*w0.x; a00.y += x0*w0.y; a00.z += x0*w0.z; a00.w += x0*w0.w;
      a01.x += x0*w1.x; a01.y += x0*w1.y; a01.z += x0*w1.z; a01.w += x0*w1.w;
      a02.x += x0*w2.x; a02.y += x0*w2.y; a02.z += x0*w2.z; a02.w += x0*w2.w;
      a03.x += x0*w3.x; a03.y += x0*w3.y; a03.z += x0*w3.z; a03.w += x0*w3.w;
      a10.x += x1*w0.x; a10.y += x1*w0.y; a10.z += x1*w0.z; a10.w += x1*w0.w;
      a11.x += x1*w1.x; a11.y += x1*w1.y; a11.z += x1*w1.z; a11.w += x1*w1.w;
      a12.x += x1*w2.x; a12.y += x1*w2.y; a12.z += x1*w2.z; a12.w += x1*w2.w;
      a13.x += x1*w3.x; a13.y += x1*w3.y; a13.z += x1*w3.z; a13.w += x1*w3.w;
    }
  }

  {
    float4* y = Y4 + (size_t)row0 * 16 + wave * 4;
    y[0] = a00; y[1] = a01; y[2] = a02; y[3] = a03;
  }
  if (ok1) {
    float4* y = Y4 + (size_t)row1 * 16 + wave * 4;
    y[0] = a10; y[1] = a11; y[2] = a12; y[3] = a13;
  }
}

// ---------------- aggregate: OUT[i][:] = relu?( sum_e nrm*XW[src][:] + b ) ----------------
// Wave-per-node; 8 edges in flight per iteration via float4 gathers.

template <bool RELU>
__global__ __launch_bounds__(256) void k_agg(const float4* __restrict__ XW4,
                                             const unsigned* __restrict__ rowptr,
                                             const uint2* __restrict__ csr,
                                             const float4* __restrict__ bias4,
                                             float4* __restrict__ OUT4) {
  int node = (int)((blockIdx.x * blockDim.x + threadIdx.x) >> 6);
  int lane = threadIdx.x & 63;
  if (node >= N_NODES) return;
  const int sub = lane & 15;
  const int grp = lane >> 4;

  unsigned beg = rowptr[node], end = rowptr[node + 1];
  float4 acc0 = {0.f, 0.f, 0.f, 0.f};
  float4 acc1 = {0.f, 0.f, 0.f, 0.f};

  for (unsigned j = beg; j < end; j += 64) {
    int nj = (int)min(64u, end - j);
    unsigned s = 0u; float nrm = 0.f;
    if (lane < nj) {
      uint2 m = csr[j + lane];
      s = m.x; nrm = __uint_as_float(m.y);
    }
    for (int k = 0; k < nj; k += 8) {
      int e0 = k + grp, e1 = k + grp + 4;
      unsigned s0 = (unsigned)__shfl((int)s, e0);
      float    n0 = __shfl(nrm, e0);
      unsigned s1 = (unsigned)__shfl((int)s, e1);
      float    n1 = __shfl(nrm, e1);
      float4 v0 = XW4[(size_t)s0 * 16 + sub];   // 16B/lane, 4 rows per instr
      float4 v1 = XW4[(size_t)s1 * 16 + sub];
      acc0.x += n0 * v0.x; acc0.y += n0 * v0.y; acc0.z += n0 * v0.z; acc0.w += n0 * v0.w;
      acc1.x += n1 * v1.x; acc1.y += n1 * v1.y; acc1.z += n1 * v1.z; acc1.w += n1 * v1.w;
    }
  }

  float4 acc;
  acc.x = acc0.x + acc1.x; acc.y = acc0.y + acc1.y;
  acc.z = acc0.z + acc1.z; acc.w = acc0.w + acc1.w;
  acc.x += __shfl_xor(acc.x, 16); acc.y += __shfl_xor(acc.y, 16);
  acc.z += __shfl_xor(acc.z, 16); acc.w += __shfl_xor(acc.w, 16);
  acc.x += __shfl_xor(acc.x, 32); acc.y += __shfl_xor(acc.y, 32);
  acc.z += __shfl_xor(acc.z, 32); acc.w += __shfl_xor(acc.w, 32);

  if (grp == 0) {
    float4 b = bias4[sub];
    acc.x += b.x; acc.y += b.y; acc.z += b.z; acc.w += b.w;
    if (RELU) {
      acc.x = fmaxf(acc.x, 0.f); acc.y = fmaxf(acc.y, 0.f);
      acc.z = fmaxf(acc.z, 0.f); acc.w = fmaxf(acc.w, 0.f);
    }
    OUT4[(size_t)node * 16 + sub] = acc;
  }
}

// ---------------- launch ----------------

extern "C" void kernel_launch(void* const* d_in, const int* in_sizes, int n_in,
                              void* d_out, int out_size, void* d_ws, size_t ws_size,
                              hipStream_t stream) {
  const float* x    = (const float*)d_in[0];
  const int*   eidx = (const int*)d_in[1];      // [2][800000], int32
  const float* W1   = (const float*)d_in[2];
  const float* b1   = (const float*)d_in[3];
  const float* W2   = (const float*)d_in[4];
  const float* b2   = (const float*)d_in[5];
  const float* W3   = (const float*)d_in[6];
  const float* b3   = (const float*)d_in[7];
  float* out = (float*)d_out;

  const int* e_src = eidx;
  const int* e_dst = eidx + N_EDGES;

  size_t off = 0;
  auto alloc = [&](size_t bytes) -> void* {
    void* p = (char*)d_ws + off;
    off += (bytes + 255) & ~(size_t)255;
    return p;
  };
  unsigned* cnt     = (unsigned*)alloc((size_t)N_NODES * 4);
  unsigned* rowptr  = (unsigned*)alloc((size_t)(N_NODES + 1) * 4);
  unsigned* fill    = (unsigned*)alloc((size_t)N_NODES * 4);
  unsigned* bsum    = (unsigned*)alloc((size_t)SCAN_B * 4);
  float*    dis     = (float*)alloc((size_t)N_NODES * 4);
  uint2*    csr     = (uint2*)alloc((size_t)E_TOT * 8);
  float*    xw      = (float*)alloc((size_t)N_NODES * 64 * 4);
  float*    h       = (float*)alloc((size_t)N_NODES * 64 * 4);

  // ---- build graph structure (per call; deterministic work) ----
  hipMemsetAsync(cnt, 0, (size_t)N_NODES * 4, stream);
  k_count<<<(N_EDGES + 255) / 256, 256, 0, stream>>>(e_dst, cnt);
  k_dis<<<(N_NODES + 255) / 256, 256, 0, stream>>>(cnt, dis);
  k_scan1<<<N_SCAN_BLOCKS, SCAN_B, 0, stream>>>(cnt, rowptr, bsum);
  k_scan2<<<1, SCAN_B, 0, stream>>>(bsum);
  k_scan3<<<(N_NODES + 255) / 256, 256, 0, stream>>>(rowptr, fill, bsum);
  k_fill<<<(E_TOT + 255) / 256, 256, 0, stream>>>(e_src, e_dst, dis, fill, csr);

  const int gemm_grid = (N_NODES + 127) / 128;        // 391
  const int agg_grid  = (N_NODES * 64 + 255) / 256;   // 12500

  // ---- layer 1: 128 -> 64, relu ----
  k_gemm<D_IN><<<gemm_grid, 256, 0, stream>>>((const float4*)x, W1, (float4*)xw);
  k_agg<true><<<agg_grid, 256, 0, stream>>>((const float4*)xw, rowptr, csr,
                                            (const float4*)b1, (float4*)h);
  // ---- layer 2: 64 -> 64, relu ----
  k_gemm<D_HID><<<gemm_grid, 256, 0, stream>>>((const float4*)h, W2, (float4*)xw);
  k_agg<true><<<agg_grid, 256, 0, stream>>>((const float4*)xw, rowptr, csr,
                                            (const float4*)b2, (float4*)h);
  // ---- layer 3: 64 -> 64, no activation ----
  k_gemm<D_HID><<<gemm_grid, 256, 0, stream>>>((const float4*)h, W3, (float4*)xw);
  k_agg<false><<<agg_grid, 256, 0, stream>>>((const float4*)xw, rowptr, csr,
                                             (const float4*)b3, (float4*)out);
}

// Round 4
// 232.741 us; speedup vs baseline: 1.4812x; 1.4812x over previous
//
#include <hip/hip_runtime.h>

#define N_NODES 50000
#define N_PAD   50048                 // padded rows for 64-row GEMM blocks
#define N_EDGES 800000
#define E_TOT   (N_EDGES + N_NODES)   // 850000 (self-loops appended)
#define D_IN    128
#define D_HID   64

#define SCAN_B        256
#define N_SCAN_BLOCKS ((N_NODES + SCAN_B - 1) / SCAN_B)   // 196

typedef __bf16 bf16x8 __attribute__((ext_vector_type(8)));
typedef __bf16 bf16x4 __attribute__((ext_vector_type(4)));
typedef float  f32x4  __attribute__((ext_vector_type(4)));

// ---------------- graph build ----------------

__global__ __launch_bounds__(256) void k_count(const int* __restrict__ dst,
                                               unsigned* __restrict__ cnt) {
  int e = blockIdx.x * blockDim.x + threadIdx.x;
  if (e < N_EDGES) atomicAdd(&cnt[dst[e]], 1u);
}

__global__ __launch_bounds__(256) void k_dis(unsigned* __restrict__ cnt,
                                             float* __restrict__ dis) {
  int i = blockIdx.x * blockDim.x + threadIdx.x;
  if (i < N_NODES) {
    unsigned c = cnt[i] + 1u;          // + self-loop
    cnt[i] = c;
    dis[i] = rsqrtf((float)c);
  }
}

__global__ __launch_bounds__(SCAN_B) void k_scan1(const unsigned* __restrict__ cnt,
                                                  unsigned* __restrict__ excl,
                                                  unsigned* __restrict__ bsum) {
  __shared__ unsigned s[SCAN_B];
  int i = blockIdx.x * SCAN_B + threadIdx.x;
  unsigned v = (i < N_NODES) ? cnt[i] : 0u;
  s[threadIdx.x] = v;
  __syncthreads();
  for (int off = 1; off < SCAN_B; off <<= 1) {
    unsigned t = (threadIdx.x >= off) ? s[threadIdx.x - off] : 0u;
    __syncthreads();
    s[threadIdx.x] += t;
    __syncthreads();
  }
  if (i < N_NODES) excl[i] = s[threadIdx.x] - v;
  if (threadIdx.x == SCAN_B - 1) bsum[blockIdx.x] = s[SCAN_B - 1];
}

__global__ __launch_bounds__(SCAN_B) void k_scan2(unsigned* __restrict__ bsum) {
  __shared__ unsigned s[SCAN_B];
  unsigned v = (threadIdx.x < N_SCAN_BLOCKS) ? bsum[threadIdx.x] : 0u;
  s[threadIdx.x] = v;
  __syncthreads();
  for (int off = 1; off < SCAN_B; off <<= 1) {
    unsigned t = (threadIdx.x >= off) ? s[threadIdx.x - off] : 0u;
    __syncthreads();
    s[threadIdx.x] += t;
    __syncthreads();
  }
  if (threadIdx.x < N_SCAN_BLOCKS) bsum[threadIdx.x] = s[threadIdx.x] - v;  // exclusive
}

__global__ __launch_bounds__(256) void k_scan3(unsigned* __restrict__ rowptr,
                                               unsigned* __restrict__ fill,
                                               const unsigned* __restrict__ bsum) {
  int i = blockIdx.x * blockDim.x + threadIdx.x;
  if (i < N_NODES) {
    unsigned r = rowptr[i] + bsum[i / SCAN_B];
    rowptr[i] = r;
    fill[i] = r;
  }
  if (i == 0) rowptr[N_NODES] = E_TOT;
}

__global__ __launch_bounds__(256) void k_fill(const int* __restrict__ esrc_in,
                                              const int* __restrict__ edst_in,
                                              const float* __restrict__ dis,
                                              unsigned* __restrict__ fill,
                                              uint2* __restrict__ csr) {
  int e = blockIdx.x * blockDim.x + threadIdx.x;
  if (e >= E_TOT) return;
  int s, d;
  if (e < N_EDGES) { s = esrc_in[e]; d = edst_in[e]; }
  else             { s = d = e - N_EDGES; }          // self-loops
  float nrm = dis[s] * dis[d];
  unsigned pos = atomicAdd(&fill[d], 1u);
  csr[pos] = make_uint2((unsigned)s, __float_as_uint(nrm));
}

// ---------------- fp32 -> (bf16 hi, bf16 lo) splits ----------------

__global__ __launch_bounds__(256) void k_split_x(const float4* __restrict__ X4,
                                                 __bf16* __restrict__ Xh,
                                                 __bf16* __restrict__ Xl) {
  int i = blockIdx.x * blockDim.x + threadIdx.x;        // over float4 groups
  if (i >= N_NODES * D_IN / 4) return;
  float4 v = X4[i];
  bf16x4 hv, lv;
#pragma unroll
  for (int j = 0; j < 4; j++) {
    float f = (&v.x)[j];
    __bf16 hb = (__bf16)f;
    hv[j] = hb;
    lv[j] = (__bf16)(f - (float)hb);
  }
  *reinterpret_cast<bf16x4*>(&Xh[i * 4]) = hv;
  *reinterpret_cast<bf16x4*>(&Xl[i * 4]) = lv;
}

// pack W[K][64] into MFMA B-fragment order:
// idx = ((ct*KS + ks)*64 + lane)*8 + j  <-  W[ks*32 + (lane>>4)*8 + j][ct*16 + (lane&15)]
template <int K>
__global__ __launch_bounds__(256) void k_split_w(const float* __restrict__ W,
                                                 __bf16* __restrict__ Bh,
                                                 __bf16* __restrict__ Bl) {
  constexpr int KS = K / 32;
  int i = blockIdx.x * blockDim.x + threadIdx.x;
  if (i >= K * 64) return;
  int j = i & 7, lane = (i >> 3) & 63, rest = i >> 9;   // rest = ct*KS + ks
  int ct = rest / KS, ks = rest - ct * KS;
  int k = ks * 32 + ((lane >> 4) << 3) + j;
  int c = ct * 16 + (lane & 15);
  float v = W[k * 64 + c];
  __bf16 hb = (__bf16)v;
  Bh[i] = hb;
  Bl[i] = (__bf16)(v - (float)hb);
}

// ---------------- dense transform via MFMA: Y[N][64] = X[N][K] @ W[K][64] ----------------
// Split-bf16 (3 products): xh@wh + xh@wl + xl@wh ~= fp32.
// Wave tile: 16 rows x 64 cols. No LDS; A from row-major global, B pre-packed.

template <int K>
__global__ __launch_bounds__(256) void k_gemm_mfma(const __bf16* __restrict__ Ah,
                                                   const __bf16* __restrict__ Al,
                                                   const __bf16* __restrict__ Bh,
                                                   const __bf16* __restrict__ Bl,
                                                   float* __restrict__ Y) {
  constexpr int KS = K / 32;
  const int tid  = threadIdx.x;
  const int wave = tid >> 6;
  const int lane = tid & 63;
  const int row0 = blockIdx.x * 64 + wave * 16;
  const size_t abase = (size_t)(row0 + (lane & 15)) * K + ((lane >> 4) << 3);

  f32x4 acc[4];
#pragma unroll
  for (int ct = 0; ct < 4; ct++) acc[ct] = (f32x4){0.f, 0.f, 0.f, 0.f};

#pragma unroll
  for (int ks = 0; ks < KS; ks++) {
    bf16x8 ah = *reinterpret_cast<const bf16x8*>(Ah + abase + ks * 32);
    bf16x8 al = *reinterpret_cast<const bf16x8*>(Al + abase + ks * 32);
#pragma unroll
    for (int ct = 0; ct < 4; ct++) {
      bf16x8 bh = *reinterpret_cast<const bf16x8*>(Bh + (size_t)((ct * KS + ks) * 64 + lane) * 8);
      bf16x8 bl = *reinterpret_cast<const bf16x8*>(Bl + (size_t)((ct * KS + ks) * 64 + lane) * 8);
      acc[ct] = __builtin_amdgcn_mfma_f32_16x16x32_bf16(ah, bh, acc[ct], 0, 0, 0);
      acc[ct] = __builtin_amdgcn_mfma_f32_16x16x32_bf16(ah, bl, acc[ct], 0, 0, 0);
      acc[ct] = __builtin_amdgcn_mfma_f32_16x16x32_bf16(al, bh, acc[ct], 0, 0, 0);
    }
  }

  // C/D: col = lane&15, row = (lane>>4)*4 + reg   [m89-verified]
  const int rbase = row0 + ((lane >> 4) << 2);
  const int c     = lane & 15;
#pragma unroll
  for (int ct = 0; ct < 4; ct++)
#pragma unroll
    for (int r = 0; r < 4; r++) {
      int row = rbase + r;
      if (row < N_NODES) Y[(size_t)row * 64 + ct * 16 + c] = acc[ct][r];
    }
}

// ---------------- aggregate: OUT[i][:] = relu?( sum_e nrm*XW[src][:] + b ) ----------------
// MODE 0: relu + write bf16 hi/lo split (feeds next MFMA gemm). MODE 1: fp32, no relu.

template <int MODE>
__global__ __launch_bounds__(256) void k_agg(const float4* __restrict__ XW4,
                                             const unsigned* __restrict__ rowptr,
                                             const uint2* __restrict__ csr,
                                             const float4* __restrict__ bias4,
                                             __bf16* __restrict__ hh,
                                             __bf16* __restrict__ hl,
                                             float4* __restrict__ OUT4) {
  int node = (int)((blockIdx.x * blockDim.x + threadIdx.x) >> 6);
  int lane = threadIdx.x & 63;
  if (node >= N_NODES) return;
  const int sub = lane & 15;
  const int grp = lane >> 4;

  unsigned beg = rowptr[node], end = rowptr[node + 1];
  float4 acc0 = {0.f, 0.f, 0.f, 0.f};
  float4 acc1 = {0.f, 0.f, 0.f, 0.f};

  for (unsigned j = beg; j < end; j += 64) {
    int nj = (int)min(64u, end - j);
    unsigned s = 0u; float nrm = 0.f;
    if (lane < nj) {
      uint2 m = csr[j + lane];
      s = m.x; nrm = __uint_as_float(m.y);
    }
    for (int k = 0; k < nj; k += 8) {
      int e0 = k + grp, e1 = k + grp + 4;
      unsigned s0 = (unsigned)__shfl((int)s, e0);
      float    n0 = __shfl(nrm, e0);
      unsigned s1 = (unsigned)__shfl((int)s, e1);
      float    n1 = __shfl(nrm, e1);
      float4 v0 = XW4[(size_t)s0 * 16 + sub];   // 16B/lane row gather
      float4 v1 = XW4[(size_t)s1 * 16 + sub];
      acc0.x += n0 * v0.x; acc0.y += n0 * v0.y; acc0.z += n0 * v0.z; acc0.w += n0 * v0.w;
      acc1.x += n1 * v1.x; acc1.y += n1 * v1.y; acc1.z += n1 * v1.z; acc1.w += n1 * v1.w;
    }
  }

  float4 acc;
  acc.x = acc0.x + acc1.x; acc.y = acc0.y + acc1.y;
  acc.z = acc0.z + acc1.z; acc.w = acc0.w + acc1.w;
  acc.x += __shfl_xor(acc.x, 16); acc.y += __shfl_xor(acc.y, 16);
  acc.z += __shfl_xor(acc.z, 16); acc.w += __shfl_xor(acc.w, 16);
  acc.x += __shfl_xor(acc.x, 32); acc.y += __shfl_xor(acc.y, 32);
  acc.z += __shfl_xor(acc.z, 32); acc.w += __shfl_xor(acc.w, 32);

  if (grp == 0) {
    float4 b = bias4[sub];
    acc.x += b.x; acc.y += b.y; acc.z += b.z; acc.w += b.w;
    if (MODE == 0) {
      acc.x = fmaxf(acc.x, 0.f); acc.y = fmaxf(acc.y, 0.f);
      acc.z = fmaxf(acc.z, 0.f); acc.w = fmaxf(acc.w, 0.f);
      bf16x4 hv, lv;
#pragma unroll
      for (int cidx = 0; cidx < 4; cidx++) {
        float f = (&acc.x)[cidx];
        __bf16 hb = (__bf16)f;
        hv[cidx] = hb;
        lv[cidx] = (__bf16)(f - (float)hb);
      }
      *reinterpret_cast<bf16x4*>(&hh[(size_t)node * 64 + sub * 4]) = hv;
      *reinterpret_cast<bf16x4*>(&hl[(size_t)node * 64 + sub * 4]) = lv;
    } else {
      OUT4[(size_t)node * 16 + sub] = acc;
    }
  }
}

// ---------------- launch ----------------

extern "C" void kernel_launch(void* const* d_in, const int* in_sizes, int n_in,
                              void* d_out, int out_size, void* d_ws, size_t ws_size,
                              hipStream_t stream) {
  const float* x    = (const float*)d_in[0];
  const int*   eidx = (const int*)d_in[1];      // [2][800000], int32
  const float* W1   = (const float*)d_in[2];
  const float* b1   = (const float*)d_in[3];
  const float* W2   = (const float*)d_in[4];
  const float* b2   = (const float*)d_in[5];
  const float* W3   = (const float*)d_in[6];
  const float* b3   = (const float*)d_in[7];
  float* out = (float*)d_out;

  const int* e_src = eidx;
  const int* e_dst = eidx + N_EDGES;

  size_t off = 0;
  auto alloc = [&](size_t bytes) -> void* {
    void* p = (char*)d_ws + off;
    off += (bytes + 255) & ~(size_t)255;
    return p;
  };
  unsigned* cnt    = (unsigned*)alloc((size_t)N_NODES * 4);
  unsigned* rowptr = (unsigned*)alloc((size_t)(N_NODES + 1) * 4);
  unsigned* fill   = (unsigned*)alloc((size_t)N_NODES * 4);
  unsigned* bsum   = (unsigned*)alloc((size_t)SCAN_B * 4);
  float*    dis    = (float*)alloc((size_t)N_NODES * 4);
  uint2*    csr    = (uint2*)alloc((size_t)E_TOT * 8);
  float*    xw     = (float*)alloc((size_t)N_PAD * 64 * 4);
  __bf16*   Xh     = (__bf16*)alloc((size_t)N_PAD * D_IN * 2);   // layer-1 A hi
  __bf16*   Xl     = (__bf16*)alloc((size_t)N_PAD * D_IN * 2);   // layer-1 A lo
  __bf16*   Wh1    = (__bf16*)alloc((size_t)D_IN * 64 * 2);
  __bf16*   Wl1    = (__bf16*)alloc((size_t)D_IN * 64 * 2);
  __bf16*   Wh2    = (__bf16*)alloc((size_t)D_HID * 64 * 2);
  __bf16*   Wl2    = (__bf16*)alloc((size_t)D_HID * 64 * 2);
  __bf16*   Wh3    = (__bf16*)alloc((size_t)D_HID * 64 * 2);
  __bf16*   Wl3    = (__bf16*)alloc((size_t)D_HID * 64 * 2);
  // h splits ping-pong inside the (dead after layer-1 gemm) Xh / Xl regions
  __bf16* hhA = Xh;                __bf16* hlA = Xh + (size_t)N_PAD * 64;
  __bf16* hhB = Xl;                __bf16* hlB = Xl + (size_t)N_PAD * 64;

  // ---- build graph structure ----
  hipMemsetAsync(cnt, 0, (size_t)N_NODES * 4, stream);
  k_count<<<(N_EDGES + 255) / 256, 256, 0, stream>>>(e_dst, cnt);
  k_dis<<<(N_NODES + 255) / 256, 256, 0, stream>>>(cnt, dis);
  k_scan1<<<N_SCAN_BLOCKS, SCAN_B, 0, stream>>>(cnt, rowptr, bsum);
  k_scan2<<<1, SCAN_B, 0, stream>>>(bsum);
  k_scan3<<<(N_NODES + 255) / 256, 256, 0, stream>>>(rowptr, fill, bsum);
  k_fill<<<(E_TOT + 255) / 256, 256, 0, stream>>>(e_src, e_dst, dis, fill, csr);

  // ---- splits ----
  k_split_x<<<(N_NODES * D_IN / 4 + 255) / 256, 256, 0, stream>>>((const float4*)x, Xh, Xl);
  k_split_w<D_IN> <<<(D_IN  * 64 + 255) / 256, 256, 0, stream>>>(W1, Wh1, Wl1);
  k_split_w<D_HID><<<(D_HID * 64 + 255) / 256, 256, 0, stream>>>(W2, Wh2, Wl2);
  k_split_w<D_HID><<<(D_HID * 64 + 255) / 256, 256, 0, stream>>>(W3, Wh3, Wl3);

  const int gemm_grid = N_PAD / 64;                   // 782
  const int agg_grid  = (N_NODES * 64 + 255) / 256;   // 12500

  // ---- layer 1: 128 -> 64, relu ----
  k_gemm_mfma<D_IN><<<gemm_grid, 256, 0, stream>>>(Xh, Xl, Wh1, Wl1, xw);
  k_agg<0><<<agg_grid, 256, 0, stream>>>((const float4*)xw, rowptr, csr,
                                         (const float4*)b1, hhA, hlA, nullptr);
  // ---- layer 2: 64 -> 64, relu ----
  k_gemm_mfma<D_HID><<<gemm_grid, 256, 0, stream>>>(hhA, hlA, Wh2, Wl2, xw);
  k_agg<0><<<agg_grid, 256, 0, stream>>>((const float4*)xw, rowptr, csr,
                                         (const float4*)b2, hhB, hlB, nullptr);
  // ---- layer 3: 64 -> 64, no activation ----
  k_gemm_mfma<D_HID><<<gemm_grid, 256, 0, stream>>>(hhB, hlB, Wh3, Wl3, xw);
  k_agg<1><<<agg_grid, 256, 0, stream>>>((const float4*)xw, rowptr, csr,
                                         (const float4*)b3, nullptr, nullptr, (float4*)out);
}

// Round 5
// 211.926 us; speedup vs baseline: 1.6267x; 1.0982x over previous
//
#include <hip/hip_runtime.h>
#include <hip/hip_fp16.h>

#define N_NODES 50000
#define N_PAD   50048                 // padded rows for 64-row GEMM blocks
#define N_EDGES 800000
#define E_TOT   (N_EDGES + N_NODES)   // 850000 (self-loops appended)
#define D_IN    128
#define D_HID   64

#define SCAN_B        256
#define N_SCAN_BLOCKS ((N_NODES + SCAN_B - 1) / SCAN_B)   // 196

typedef __bf16 bf16x8 __attribute__((ext_vector_type(8)));
typedef __bf16 bf16x4 __attribute__((ext_vector_type(4)));
typedef float  f32x4  __attribute__((ext_vector_type(4)));

// ---------------- graph build ----------------

__global__ __launch_bounds__(256) void k_count(const int* __restrict__ dst,
                                               unsigned* __restrict__ cnt) {
  int tid = blockIdx.x * 256 + threadIdx.x;
  int stride = gridDim.x * 256;
  for (int e = tid; e < N_EDGES; e += stride)   // 4 independent atomics in flight
    atomicAdd(&cnt[dst[e]], 1u);
}

// scan1 also computes deg (=cnt+1 self-loop) and dis = rsqrt(deg)
__global__ __launch_bounds__(SCAN_B) void k_scan1(const unsigned* __restrict__ cnt,
                                                  float* __restrict__ dis,
                                                  unsigned* __restrict__ excl,
                                                  unsigned* __restrict__ bsum) {
  __shared__ unsigned s[SCAN_B];
  int i = blockIdx.x * SCAN_B + threadIdx.x;
  unsigned v = 0u;
  if (i < N_NODES) {
    v = cnt[i] + 1u;                  // + self-loop
    dis[i] = rsqrtf((float)v);
  }
  s[threadIdx.x] = v;
  __syncthreads();
  for (int off = 1; off < SCAN_B; off <<= 1) {
    unsigned t = (threadIdx.x >= off) ? s[threadIdx.x - off] : 0u;
    __syncthreads();
    s[threadIdx.x] += t;
    __syncthreads();
  }
  if (i < N_NODES) excl[i] = s[threadIdx.x] - v;
  if (threadIdx.x == SCAN_B - 1) bsum[blockIdx.x] = s[SCAN_B - 1];
}

__global__ __launch_bounds__(SCAN_B) void k_scan2(unsigned* __restrict__ bsum) {
  __shared__ unsigned s[SCAN_B];
  unsigned v = (threadIdx.x < N_SCAN_BLOCKS) ? bsum[threadIdx.x] : 0u;
  s[threadIdx.x] = v;
  __syncthreads();
  for (int off = 1; off < SCAN_B; off <<= 1) {
    unsigned t = (threadIdx.x >= off) ? s[threadIdx.x - off] : 0u;
    __syncthreads();
    s[threadIdx.x] += t;
    __syncthreads();
  }
  if (threadIdx.x < N_SCAN_BLOCKS) bsum[threadIdx.x] = s[threadIdx.x] - v;  // exclusive
}

__global__ __launch_bounds__(256) void k_scan3(unsigned* __restrict__ rowptr,
                                               unsigned* __restrict__ fill,
                                               const unsigned* __restrict__ bsum) {
  int i = blockIdx.x * blockDim.x + threadIdx.x;
  if (i < N_NODES) {
    unsigned r = rowptr[i] + bsum[i / SCAN_B];
    rowptr[i] = r;
    fill[i] = r;
  }
  if (i == 0) rowptr[N_NODES] = E_TOT;
}

// CSR fill: 4B payload (src only); norm recomputed in k_agg from dis table.
__global__ __launch_bounds__(256) void k_fill(const int* __restrict__ esrc_in,
                                              const int* __restrict__ edst_in,
                                              unsigned* __restrict__ fill,
                                              unsigned* __restrict__ csr) {
  int tid = blockIdx.x * 256 + threadIdx.x;
  int stride = gridDim.x * 256;
  for (int e = tid; e < E_TOT; e += stride) {
    int s, d;
    if (e < N_EDGES) { s = esrc_in[e]; d = edst_in[e]; }
    else             { s = d = e - N_EDGES; }          // self-loops
    unsigned pos = atomicAdd(&fill[d], 1u);
    csr[pos] = (unsigned)s;
  }
}

// ---------------- W -> MFMA-B-fragment-order bf16 hi/lo (all 3 in one launch) ----------------
// idx = ((ct*KS + ks)*64 + lane)*8 + j  <-  W[ks*32 + (lane>>4)*8 + j][ct*16 + (lane&15)]

template <int K>
__device__ inline void pack_w(const float* __restrict__ W,
                              __bf16* __restrict__ Bh, __bf16* __restrict__ Bl, int i) {
  constexpr int KS = K / 32;
  int j = i & 7, lane = (i >> 3) & 63, rest = i >> 9;
  int ct = rest / KS, ks = rest - ct * KS;
  int k = ks * 32 + ((lane >> 4) << 3) + j;
  int c = ct * 16 + (lane & 15);
  float v = W[k * 64 + c];
  __bf16 hb = (__bf16)v;
  Bh[i] = hb;
  Bl[i] = (__bf16)(v - (float)hb);
}

__global__ __launch_bounds__(256) void k_split_w3(const float* __restrict__ W1,
                                                  const float* __restrict__ W2,
                                                  const float* __restrict__ W3,
                                                  __bf16* __restrict__ Wh1, __bf16* __restrict__ Wl1,
                                                  __bf16* __restrict__ Wh2, __bf16* __restrict__ Wl2,
                                                  __bf16* __restrict__ Wh3, __bf16* __restrict__ Wl3) {
  int b = blockIdx.x, t = threadIdx.x;
  if (b < 32)      pack_w<D_IN >(W1, Wh1, Wl1, b * 256 + t);          // 8192 elems
  else if (b < 48) pack_w<D_HID>(W2, Wh2, Wl2, (b - 32) * 256 + t);   // 4096
  else             pack_w<D_HID>(W3, Wh3, Wl3, (b - 48) * 256 + t);   // 4096
}

// ---------------- dense transform via MFMA: Y[N][64] = A[N][K] @ W[K][64], Y in fp16 ----------------
// Split-bf16 (3 products): ah@bh + ah@bl + al@bh ~= fp32.
// FIRST: A is fp32 x, split in-register. Else: pre-split bf16 Ah/Al.

template <int K, bool FIRST>
__global__ __launch_bounds__(256) void k_gemm_mfma(const float* __restrict__ Xf,
                                                   const __bf16* __restrict__ Ah,
                                                   const __bf16* __restrict__ Al,
                                                   const __bf16* __restrict__ Bh,
                                                   const __bf16* __restrict__ Bl,
                                                   __half* __restrict__ Y) {
  constexpr int KS = K / 32;
  const int tid  = threadIdx.x;
  const int wave = tid >> 6;
  const int lane = tid & 63;
  const int row0 = blockIdx.x * 64 + wave * 16;
  const int row_a = FIRST ? min(row0 + (lane & 15), N_NODES - 1)   // clamp: x has exactly N_NODES rows
                          : row0 + (lane & 15);
  const int q8 = (lane >> 4) << 3;                                  // k-offset within 32-chunk

  f32x4 acc[4];
#pragma unroll
  for (int ct = 0; ct < 4; ct++) acc[ct] = (f32x4){0.f, 0.f, 0.f, 0.f};

#pragma unroll
  for (int ks = 0; ks < KS; ks++) {
    bf16x8 ah, al;
    if (FIRST) {
      const float4* xr4 = reinterpret_cast<const float4*>(Xf + (size_t)row_a * K);
      float4 f0 = xr4[ks * 8 + (q8 >> 2) + 0];
      float4 f1 = xr4[ks * 8 + (q8 >> 2) + 1];
#pragma unroll
      for (int j = 0; j < 4; j++) {
        float a0 = (&f0.x)[j], a1 = (&f1.x)[j];
        __bf16 h0 = (__bf16)a0, h1 = (__bf16)a1;
        ah[j] = h0;     al[j] = (__bf16)(a0 - (float)h0);
        ah[4 + j] = h1; al[4 + j] = (__bf16)(a1 - (float)h1);
      }
    } else {
      size_t abase = (size_t)row_a * K + q8 + ks * 32;
      ah = *reinterpret_cast<const bf16x8*>(Ah + abase);
      al = *reinterpret_cast<const bf16x8*>(Al + abase);
    }
#pragma unroll
    for (int ct = 0; ct < 4; ct++) {
      bf16x8 bh = *reinterpret_cast<const bf16x8*>(Bh + (size_t)((ct * KS + ks) * 64 + lane) * 8);
      bf16x8 bl = *reinterpret_cast<const bf16x8*>(Bl + (size_t)((ct * KS + ks) * 64 + lane) * 8);
      acc[ct] = __builtin_amdgcn_mfma_f32_16x16x32_bf16(ah, bh, acc[ct], 0, 0, 0);
      acc[ct] = __builtin_amdgcn_mfma_f32_16x16x32_bf16(ah, bl, acc[ct], 0, 0, 0);
      acc[ct] = __builtin_amdgcn_mfma_f32_16x16x32_bf16(al, bh, acc[ct], 0, 0, 0);
    }
  }

  // C/D: col = lane&15, row = (lane>>4)*4 + reg   [m89-verified]
  const int rbase = row0 + ((lane >> 4) << 2);
  const int c     = lane & 15;
#pragma unroll
  for (int ct = 0; ct < 4; ct++)
#pragma unroll
    for (int r = 0; r < 4; r++) {
      int row = rbase + r;
      if (row < N_NODES)
        Y[(size_t)row * 64 + ct * 16 + c] = __float2half_rn(acc[ct][r]);
    }
}

// ---------------- aggregate: OUT[i][:] = relu?( sum_e nrm*XW[src][:] + b ) ----------------
// XW is fp16 [N][64] (128B rows). Wave-per-node, 8 edges in flight, 8B gathers.
// MODE 0: relu + write bf16 hi/lo split (feeds next MFMA gemm). MODE 1: fp32 out, no relu.

template <int MODE>
__global__ __launch_bounds__(256) void k_agg(const uint2* __restrict__ XW2,
                                             const unsigned* __restrict__ rowptr,
                                             const unsigned* __restrict__ csr,
                                             const float* __restrict__ dis,
                                             const float4* __restrict__ bias4,
                                             __bf16* __restrict__ hh,
                                             __bf16* __restrict__ hl,
                                             float4* __restrict__ OUT4) {
  int node = (int)((blockIdx.x * blockDim.x + threadIdx.x) >> 6);
  int lane = threadIdx.x & 63;
  if (node >= N_NODES) return;
  const int sub = lane & 15;
  const int grp = lane >> 4;

  const float disd = dis[node];
  unsigned beg = rowptr[node], end = rowptr[node + 1];
  float4 acc0 = {0.f, 0.f, 0.f, 0.f};
  float4 acc1 = {0.f, 0.f, 0.f, 0.f};

  for (unsigned j = beg; j < end; j += 64) {
    int nj = (int)min(64u, end - j);
    unsigned s = 0u; float nrm = 0.f;
    if (lane < nj) {
      s = csr[j + lane];                 // 4B coalesced
      nrm = dis[s] * disd;               // dis: 200KB, L2-resident gather
    }
    for (int k = 0; k < nj; k += 8) {
      int e0 = k + grp, e1 = k + grp + 4;
      unsigned s0 = (unsigned)__shfl((int)s, e0);
      float    n0 = __shfl(nrm, e0);
      unsigned s1 = (unsigned)__shfl((int)s, e1);
      float    n1 = __shfl(nrm, e1);
      uint2 v0 = XW2[(size_t)s0 * 16 + sub];    // 8B/lane fp16 row gather
      uint2 v1 = XW2[(size_t)s1 * 16 + sub];
      float2 a01 = __half22float2(*reinterpret_cast<__half2*>(&v0.x));
      float2 a23 = __half22float2(*reinterpret_cast<__half2*>(&v0.y));
      float2 b01 = __half22float2(*reinterpret_cast<__half2*>(&v1.x));
      float2 b23 = __half22float2(*reinterpret_cast<__half2*>(&v1.y));
      acc0.x += n0 * a01.x; acc0.y += n0 * a01.y; acc0.z += n0 * a23.x; acc0.w += n0 * a23.y;
      acc1.x += n1 * b01.x; acc1.y += n1 * b01.y; acc1.z += n1 * b23.x; acc1.w += n1 * b23.y;
    }
  }

  float4 acc;
  acc.x = acc0.x + acc1.x; acc.y = acc0.y + acc1.y;
  acc.z = acc0.z + acc1.z; acc.w = acc0.w + acc1.w;
  acc.x += __shfl_xor(acc.x, 16); acc.y += __shfl_xor(acc.y, 16);
  acc.z += __shfl_xor(acc.z, 16); acc.w += __shfl_xor(acc.w, 16);
  acc.x += __shfl_xor(acc.x, 32); acc.y += __shfl_xor(acc.y, 32);
  acc.z += __shfl_xor(acc.z, 32); acc.w += __shfl_xor(acc.w, 32);

  if (grp == 0) {
    float4 b = bias4[sub];
    acc.x += b.x; acc.y += b.y; acc.z += b.z; acc.w += b.w;
    if (MODE == 0) {
      acc.x = fmaxf(acc.x, 0.f); acc.y = fmaxf(acc.y, 0.f);
      acc.z = fmaxf(acc.z, 0.f); acc.w = fmaxf(acc.w, 0.f);
      bf16x4 hv, lv;
#pragma unroll
      for (int cidx = 0; cidx < 4; cidx++) {
        float f = (&acc.x)[cidx];
        __bf16 hb = (__bf16)f;
        hv[cidx] = hb;
        lv[cidx] = (__bf16)(f - (float)hb);
      }
      *reinterpret_cast<bf16x4*>(&hh[(size_t)node * 64 + sub * 4]) = hv;
      *reinterpret_cast<bf16x4*>(&hl[(size_t)node * 64 + sub * 4]) = lv;
    } else {
      OUT4[(size_t)node * 16 + sub] = acc;
    }
  }
}

// ---------------- launch ----------------

extern "C" void kernel_launch(void* const* d_in, const int* in_sizes, int n_in,
                              void* d_out, int out_size, void* d_ws, size_t ws_size,
                              hipStream_t stream) {
  const float* x    = (const float*)d_in[0];
  const int*   eidx = (const int*)d_in[1];      // [2][800000], int32
  const float* W1   = (const float*)d_in[2];
  const float* b1   = (const float*)d_in[3];
  const float* W2   = (const float*)d_in[4];
  const float* b2   = (const float*)d_in[5];
  const float* W3   = (const float*)d_in[6];
  const float* b3   = (const float*)d_in[7];
  float* out = (float*)d_out;

  const int* e_src = eidx;
  const int* e_dst = eidx + N_EDGES;

  size_t off = 0;
  auto alloc = [&](size_t bytes) -> void* {
    void* p = (char*)d_ws + off;
    off += (bytes + 255) & ~(size_t)255;
    return p;
  };
  unsigned* cnt    = (unsigned*)alloc((size_t)N_NODES * 4);
  unsigned* rowptr = (unsigned*)alloc((size_t)(N_NODES + 1) * 4);
  unsigned* fill   = (unsigned*)alloc((size_t)N_NODES * 4);
  unsigned* bsum   = (unsigned*)alloc((size_t)SCAN_B * 4);
  float*    dis    = (float*)alloc((size_t)N_NODES * 4);
  unsigned* csr    = (unsigned*)alloc((size_t)E_TOT * 4);
  __half*   xw     = (__half*)alloc((size_t)N_PAD * 64 * 2);
  __bf16*   hhA    = (__bf16*)alloc((size_t)N_PAD * 64 * 2);
  __bf16*   hlA    = (__bf16*)alloc((size_t)N_PAD * 64 * 2);
  __bf16*   hhB    = (__bf16*)alloc((size_t)N_PAD * 64 * 2);
  __bf16*   hlB    = (__bf16*)alloc((size_t)N_PAD * 64 * 2);
  __bf16*   Wh1    = (__bf16*)alloc((size_t)D_IN * 64 * 2);
  __bf16*   Wl1    = (__bf16*)alloc((size_t)D_IN * 64 * 2);
  __bf16*   Wh2    = (__bf16*)alloc((size_t)D_HID * 64 * 2);
  __bf16*   Wl2    = (__bf16*)alloc((size_t)D_HID * 64 * 2);
  __bf16*   Wh3    = (__bf16*)alloc((size_t)D_HID * 64 * 2);
  __bf16*   Wl3    = (__bf16*)alloc((size_t)D_HID * 64 * 2);

  // ---- build graph structure ----
  hipMemsetAsync(cnt, 0, (size_t)N_NODES * 4, stream);
  k_count<<<782, 256, 0, stream>>>(e_dst, cnt);                       // ~4 edges/thread
  k_scan1<<<N_SCAN_BLOCKS, SCAN_B, 0, stream>>>(cnt, dis, rowptr, bsum);
  k_scan2<<<1, SCAN_B, 0, stream>>>(bsum);
  k_scan3<<<(N_NODES + 255) / 256, 256, 0, stream>>>(rowptr, fill, bsum);
  k_fill<<<831, 256, 0, stream>>>(e_src, e_dst, fill, csr);           // ~4 edges/thread
  k_split_w3<<<64, 256, 0, stream>>>(W1, W2, W3, Wh1, Wl1, Wh2, Wl2, Wh3, Wl3);

  const int gemm_grid = N_PAD / 64;                   // 782
  const int agg_grid  = (N_NODES * 64 + 255) / 256;   // 12500

  // ---- layer 1: 128 -> 64, relu ----
  k_gemm_mfma<D_IN, true><<<gemm_grid, 256, 0, stream>>>(x, nullptr, nullptr, Wh1, Wl1, xw);
  k_agg<0><<<agg_grid, 256, 0, stream>>>((const uint2*)xw, rowptr, csr, dis,
                                         (const float4*)b1, hhA, hlA, nullptr);
  // ---- layer 2: 64 -> 64, relu ----
  k_gemm_mfma<D_HID, false><<<gemm_grid, 256, 0, stream>>>(nullptr, hhA, hlA, Wh2, Wl2, xw);
  k_agg<0><<<agg_grid, 256, 0, stream>>>((const uint2*)xw, rowptr, csr, dis,
                                         (const float4*)b2, hhB, hlB, nullptr);
  // ---- layer 3: 64 -> 64, no activation ----
  k_gemm_mfma<D_HID, false><<<gemm_grid, 256, 0, stream>>>(nullptr, hhB, hlB, Wh3, Wl3, xw);
  k_agg<1><<<agg_grid, 256, 0, stream>>>((const uint2*)xw, rowptr, csr, dis,
                                         (const float4*)b3, nullptr, nullptr, (float4*)out);
}

// Round 6
// 155.651 us; speedup vs baseline: 2.2148x; 1.3615x over previous
//
#include <hip/hip_runtime.h>
#include <hip/hip_fp16.h>

#define N_NODES 50000
#define N_PAD   50048                 // padded rows for 64-row GEMM blocks
#define N_EDGES 800000
#define E_TOT   (N_EDGES + N_NODES)   // 850000 (self-loops inserted per node)
#define D_IN    128
#define D_HID   64

#define NB       196                  // buckets of 256 nodes: (50000+255)/256
#define EB_CHUNK 4096                 // edges per binning block

typedef __bf16 bf16x8 __attribute__((ext_vector_type(8)));
typedef __bf16 bf16x4 __attribute__((ext_vector_type(4)));
typedef float  f32x4  __attribute__((ext_vector_type(4)));

// ---------------- graph build: binned CSR (no global random scatter) ----------------

// Pass A: global bucket histogram via LDS
__global__ __launch_bounds__(256) void k_binc(const int* __restrict__ dst,
                                              unsigned* __restrict__ bucket_cnt) {
  __shared__ unsigned lh[256];
  int t = threadIdx.x;
  lh[t] = 0;
  __syncthreads();
  int base = blockIdx.x * EB_CHUNK;
  int endv = min(base + EB_CHUNK, N_EDGES);
  for (int e = base + t; e < endv; e += 256)
    atomicAdd(&lh[((unsigned)dst[e]) >> 8], 1u);
  __syncthreads();
  if (t < NB && lh[t]) atomicAdd(&bucket_cnt[t], lh[t]);
}

// Scan: bucket bases for temp (edges only) and csr (edges + self-loops)
__global__ __launch_bounds__(256) void k_bscan(const unsigned* __restrict__ bucket_cnt,
                                               unsigned* __restrict__ bucket_ebase,
                                               unsigned* __restrict__ bucket_fill,
                                               unsigned* __restrict__ bucket_cbase,
                                               unsigned* __restrict__ rowptr) {
  __shared__ unsigned se[256], sc[256];
  int t = threadIdx.x;
  unsigned cnt   = (t < NB) ? bucket_cnt[t] : 0u;
  unsigned nodes = (t < NB) ? (unsigned)min(256, N_NODES - t * 256) : 0u;
  unsigned ctot  = cnt + nodes;
  se[t] = cnt; sc[t] = ctot;
  __syncthreads();
  for (int off = 1; off < 256; off <<= 1) {
    unsigned a = (t >= off) ? se[t - off] : 0u;
    unsigned b = (t >= off) ? sc[t - off] : 0u;
    __syncthreads();
    se[t] += a; sc[t] += b;
    __syncthreads();
  }
  if (t < NB) {
    bucket_ebase[t] = se[t] - cnt;
    bucket_fill[t]  = se[t] - cnt;
    bucket_cbase[t] = sc[t] - ctot;
  }
  if (t == 0) rowptr[N_NODES] = E_TOT;
}

// Pass B: scatter packed edges (src | dstlocal<<16) into dense per-bucket runs
__global__ __launch_bounds__(256) void k_bins(const int* __restrict__ src,
                                              const int* __restrict__ dst,
                                              unsigned* __restrict__ bucket_fill,
                                              unsigned* __restrict__ temp) {
  __shared__ unsigned lh[256], lcur[256];
  int t = threadIdx.x;
  lh[t] = 0;
  __syncthreads();
  int base = blockIdx.x * EB_CHUNK;
  int endv = min(base + EB_CHUNK, N_EDGES);
  for (int e = base + t; e < endv; e += 256)
    atomicAdd(&lh[((unsigned)dst[e]) >> 8], 1u);
  __syncthreads();
  if (t < NB && lh[t]) lcur[t] = atomicAdd(&bucket_fill[t], lh[t]);
  __syncthreads();
  for (int e = base + t; e < endv; e += 256) {
    unsigned d = (unsigned)dst[e];
    unsigned b = d >> 8;
    unsigned pos = atomicAdd(&lcur[b], 1u);
    temp[pos] = (unsigned)src[e] | ((d & 255u) << 16);   // src < 2^16, dstlocal 8b
  }
}

// Pass C: per-bucket CSR finalize — rowptr, dis, self-loop, edge scatter (L2-local)
__global__ __launch_bounds__(256) void k_csr(const unsigned* __restrict__ temp,
                                             const unsigned* __restrict__ bucket_ebase,
                                             const unsigned* __restrict__ bucket_cnt,
                                             const unsigned* __restrict__ bucket_cbase,
                                             unsigned* __restrict__ rowptr,
                                             float* __restrict__ dis,
                                             unsigned* __restrict__ csr) {
  __shared__ unsigned hist[256], sscan[256], lfill[256];
  int b = blockIdx.x, t = threadIdx.x;
  unsigned ebase = bucket_ebase[b], ecnt = bucket_cnt[b], cbase = bucket_cbase[b];
  int nodes = min(256, N_NODES - b * 256);
  hist[t] = 0;
  __syncthreads();
  for (unsigned i = t; i < ecnt; i += 256)
    atomicAdd(&hist[(temp[ebase + i] >> 16) & 255u], 1u);
  __syncthreads();
  unsigned deg = (t < nodes) ? hist[t] + 1u : 0u;        // + self-loop
  sscan[t] = deg;
  __syncthreads();
  for (int off = 1; off < 256; off <<= 1) {
    unsigned x = (t >= off) ? sscan[t - off] : 0u;
    __syncthreads();
    sscan[t] += x;
    __syncthreads();
  }
  unsigned excl = sscan[t] - deg;
  if (t < nodes) {
    int node = b * 256 + t;
    rowptr[node] = cbase + excl;
    dis[node] = rsqrtf((float)deg);
    csr[cbase + excl] = (unsigned)node;                  // self-loop entry
  }
  lfill[t] = excl + 1u;
  __syncthreads();
  for (unsigned i = t; i < ecnt; i += 256) {
    unsigned v = temp[ebase + i];
    unsigned d = (v >> 16) & 255u;
    unsigned pos = atomicAdd(&lfill[d], 1u);
    csr[cbase + pos] = v & 0xFFFFu;                      // src
  }
}

// ---------------- W -> MFMA-B-fragment-order bf16 hi/lo (all 3 in one launch) ----------------

template <int K>
__device__ inline void pack_w(const float* __restrict__ W,
                              __bf16* __restrict__ Bh, __bf16* __restrict__ Bl, int i) {
  constexpr int KS = K / 32;
  int j = i & 7, lane = (i >> 3) & 63, rest = i >> 9;
  int ct = rest / KS, ks = rest - ct * KS;
  int k = ks * 32 + ((lane >> 4) << 3) + j;
  int c = ct * 16 + (lane & 15);
  float v = W[k * 64 + c];
  __bf16 hb = (__bf16)v;
  Bh[i] = hb;
  Bl[i] = (__bf16)(v - (float)hb);
}

__global__ __launch_bounds__(256) void k_split_w3(const float* __restrict__ W1,
                                                  const float* __restrict__ W2,
                                                  const float* __restrict__ W3,
                                                  __bf16* __restrict__ Wh1, __bf16* __restrict__ Wl1,
                                                  __bf16* __restrict__ Wh2, __bf16* __restrict__ Wl2,
                                                  __bf16* __restrict__ Wh3, __bf16* __restrict__ Wl3) {
  int b = blockIdx.x, t = threadIdx.x;
  if (b < 32)      pack_w<D_IN >(W1, Wh1, Wl1, b * 256 + t);
  else if (b < 48) pack_w<D_HID>(W2, Wh2, Wl2, (b - 32) * 256 + t);
  else             pack_w<D_HID>(W3, Wh3, Wl3, (b - 48) * 256 + t);
}

// ---------------- dense transform via MFMA: Y[N][64] = A[N][K] @ W[K][64], Y in fp16 ----------------

template <int K, bool FIRST>
__global__ __launch_bounds__(256) void k_gemm_mfma(const float* __restrict__ Xf,
                                                   const __bf16* __restrict__ Ah,
                                                   const __bf16* __restrict__ Al,
                                                   const __bf16* __restrict__ Bh,
                                                   const __bf16* __restrict__ Bl,
                                                   __half* __restrict__ Y) {
  constexpr int KS = K / 32;
  const int tid  = threadIdx.x;
  const int wave = tid >> 6;
  const int lane = tid & 63;
  const int row0 = blockIdx.x * 64 + wave * 16;
  const int row_a = FIRST ? min(row0 + (lane & 15), N_NODES - 1)
                          : row0 + (lane & 15);
  const int q8 = (lane >> 4) << 3;

  f32x4 acc[4];
#pragma unroll
  for (int ct = 0; ct < 4; ct++) acc[ct] = (f32x4){0.f, 0.f, 0.f, 0.f};

#pragma unroll
  for (int ks = 0; ks < KS; ks++) {
    bf16x8 ah, al;
    if (FIRST) {
      const float4* xr4 = reinterpret_cast<const float4*>(Xf + (size_t)row_a * K);
      float4 f0 = xr4[ks * 8 + (q8 >> 2) + 0];
      float4 f1 = xr4[ks * 8 + (q8 >> 2) + 1];
#pragma unroll
      for (int j = 0; j < 4; j++) {
        float a0 = (&f0.x)[j], a1 = (&f1.x)[j];
        __bf16 h0 = (__bf16)a0, h1 = (__bf16)a1;
        ah[j] = h0;     al[j] = (__bf16)(a0 - (float)h0);
        ah[4 + j] = h1; al[4 + j] = (__bf16)(a1 - (float)h1);
      }
    } else {
      size_t abase = (size_t)row_a * K + q8 + ks * 32;
      ah = *reinterpret_cast<const bf16x8*>(Ah + abase);
      al = *reinterpret_cast<const bf16x8*>(Al + abase);
    }
#pragma unroll
    for (int ct = 0; ct < 4; ct++) {
      bf16x8 bh = *reinterpret_cast<const bf16x8*>(Bh + (size_t)((ct * KS + ks) * 64 + lane) * 8);
      bf16x8 bl = *reinterpret_cast<const bf16x8*>(Bl + (size_t)((ct * KS + ks) * 64 + lane) * 8);
      acc[ct] = __builtin_amdgcn_mfma_f32_16x16x32_bf16(ah, bh, acc[ct], 0, 0, 0);
      acc[ct] = __builtin_amdgcn_mfma_f32_16x16x32_bf16(ah, bl, acc[ct], 0, 0, 0);
      acc[ct] = __builtin_amdgcn_mfma_f32_16x16x32_bf16(al, bh, acc[ct], 0, 0, 0);
    }
  }

  const int rbase = row0 + ((lane >> 4) << 2);
  const int c     = lane & 15;
#pragma unroll
  for (int ct = 0; ct < 4; ct++)
#pragma unroll
    for (int r = 0; r < 4; r++) {
      int row = rbase + r;
      if (row < N_NODES)
        Y[(size_t)row * 64 + ct * 16 + c] = __float2half_rn(acc[ct][r]);
    }
}

// ---------------- aggregate: OUT[i][:] = relu?( sum_e nrm*XW[src][:] + b ) ----------------

template <int MODE>
__global__ __launch_bounds__(256) void k_agg(const uint2* __restrict__ XW2,
                                             const unsigned* __restrict__ rowptr,
                                             const unsigned* __restrict__ csr,
                                             const float* __restrict__ dis,
                                             const float4* __restrict__ bias4,
                                             __bf16* __restrict__ hh,
                                             __bf16* __restrict__ hl,
                                             float4* __restrict__ OUT4) {
  int node = (int)((blockIdx.x * blockDim.x + threadIdx.x) >> 6);
  int lane = threadIdx.x & 63;
  if (node >= N_NODES) return;
  const int sub = lane & 15;
  const int grp = lane >> 4;

  const float disd = dis[node];
  unsigned beg = rowptr[node], end = rowptr[node + 1];
  float4 acc0 = {0.f, 0.f, 0.f, 0.f};
  float4 acc1 = {0.f, 0.f, 0.f, 0.f};

  for (unsigned j = beg; j < end; j += 64) {
    int nj = (int)min(64u, end - j);
    unsigned s = 0u; float nrm = 0.f;
    if (lane < nj) {
      s = csr[j + lane];
      nrm = dis[s] * disd;
    }
    for (int k = 0; k < nj; k += 8) {
      int e0 = k + grp, e1 = k + grp + 4;
      unsigned s0 = (unsigned)__shfl((int)s, e0);
      float    n0 = __shfl(nrm, e0);
      unsigned s1 = (unsigned)__shfl((int)s, e1);
      float    n1 = __shfl(nrm, e1);
      uint2 v0 = XW2[(size_t)s0 * 16 + sub];
      uint2 v1 = XW2[(size_t)s1 * 16 + sub];
      float2 a01 = __half22float2(*reinterpret_cast<__half2*>(&v0.x));
      float2 a23 = __half22float2(*reinterpret_cast<__half2*>(&v0.y));
      float2 b01 = __half22float2(*reinterpret_cast<__half2*>(&v1.x));
      float2 b23 = __half22float2(*reinterpret_cast<__half2*>(&v1.y));
      acc0.x += n0 * a01.x; acc0.y += n0 * a01.y; acc0.z += n0 * a23.x; acc0.w += n0 * a23.y;
      acc1.x += n1 * b01.x; acc1.y += n1 * b01.y; acc1.z += n1 * b23.x; acc1.w += n1 * b23.y;
    }
  }

  float4 acc;
  acc.x = acc0.x + acc1.x; acc.y = acc0.y + acc1.y;
  acc.z = acc0.z + acc1.z; acc.w = acc0.w + acc1.w;
  acc.x += __shfl_xor(acc.x, 16); acc.y += __shfl_xor(acc.y, 16);
  acc.z += __shfl_xor(acc.z, 16); acc.w += __shfl_xor(acc.w, 16);
  acc.x += __shfl_xor(acc.x, 32); acc.y += __shfl_xor(acc.y, 32);
  acc.z += __shfl_xor(acc.z, 32); acc.w += __shfl_xor(acc.w, 32);

  if (grp == 0) {
    float4 b = bias4[sub];
    acc.x += b.x; acc.y += b.y; acc.z += b.z; acc.w += b.w;
    if (MODE == 0) {
      acc.x = fmaxf(acc.x, 0.f); acc.y = fmaxf(acc.y, 0.f);
      acc.z = fmaxf(acc.z, 0.f); acc.w = fmaxf(acc.w, 0.f);
      bf16x4 hv, lv;
#pragma unroll
      for (int cidx = 0; cidx < 4; cidx++) {
        float f = (&acc.x)[cidx];
        __bf16 hb = (__bf16)f;
        hv[cidx] = hb;
        lv[cidx] = (__bf16)(f - (float)hb);
      }
      *reinterpret_cast<bf16x4*>(&hh[(size_t)node * 64 + sub * 4]) = hv;
      *reinterpret_cast<bf16x4*>(&hl[(size_t)node * 64 + sub * 4]) = lv;
    } else {
      OUT4[(size_t)node * 16 + sub] = acc;
    }
  }
}

// ---------------- launch ----------------

extern "C" void kernel_launch(void* const* d_in, const int* in_sizes, int n_in,
                              void* d_out, int out_size, void* d_ws, size_t ws_size,
                              hipStream_t stream) {
  const float* x    = (const float*)d_in[0];
  const int*   eidx = (const int*)d_in[1];      // [2][800000], int32
  const float* W1   = (const float*)d_in[2];
  const float* b1   = (const float*)d_in[3];
  const float* W2   = (const float*)d_in[4];
  const float* b2   = (const float*)d_in[5];
  const float* W3   = (const float*)d_in[6];
  const float* b3   = (const float*)d_in[7];
  float* out = (float*)d_out;

  const int* e_src = eidx;
  const int* e_dst = eidx + N_EDGES;

  size_t off = 0;
  auto alloc = [&](size_t bytes) -> void* {
    void* p = (char*)d_ws + off;
    off += (bytes + 255) & ~(size_t)255;
    return p;
  };
  unsigned* rowptr  = (unsigned*)alloc((size_t)(N_NODES + 1) * 4);
  float*    dis     = (float*)alloc((size_t)N_NODES * 4);
  unsigned* csr     = (unsigned*)alloc((size_t)E_TOT * 4);
  unsigned* temp    = (unsigned*)alloc((size_t)N_EDGES * 4);
  unsigned* bcnt    = (unsigned*)alloc(256 * 4);
  unsigned* bebase  = (unsigned*)alloc(256 * 4);
  unsigned* bfill   = (unsigned*)alloc(256 * 4);
  unsigned* bcbase  = (unsigned*)alloc(256 * 4);
  __half*   xw      = (__half*)alloc((size_t)N_PAD * 64 * 2);
  __bf16*   hhA     = (__bf16*)alloc((size_t)N_PAD * 64 * 2);
  __bf16*   hlA     = (__bf16*)alloc((size_t)N_PAD * 64 * 2);
  __bf16*   hhB     = (__bf16*)alloc((size_t)N_PAD * 64 * 2);
  __bf16*   hlB     = (__bf16*)alloc((size_t)N_PAD * 64 * 2);
  __bf16*   Wh1     = (__bf16*)alloc((size_t)D_IN * 64 * 2);
  __bf16*   Wl1     = (__bf16*)alloc((size_t)D_IN * 64 * 2);
  __bf16*   Wh2     = (__bf16*)alloc((size_t)D_HID * 64 * 2);
  __bf16*   Wl2     = (__bf16*)alloc((size_t)D_HID * 64 * 2);
  __bf16*   Wh3     = (__bf16*)alloc((size_t)D_HID * 64 * 2);
  __bf16*   Wl3     = (__bf16*)alloc((size_t)D_HID * 64 * 2);

  const int bin_grid = (N_EDGES + EB_CHUNK - 1) / EB_CHUNK;   // 196

  // ---- binned CSR build ----
  hipMemsetAsync(bcnt, 0, 256 * 4, stream);
  k_binc <<<bin_grid, 256, 0, stream>>>(e_dst, bcnt);
  k_bscan<<<1,        256, 0, stream>>>(bcnt, bebase, bfill, bcbase, rowptr);
  k_bins <<<bin_grid, 256, 0, stream>>>(e_src, e_dst, bfill, temp);
  k_csr  <<<NB,       256, 0, stream>>>(temp, bebase, bcnt, bcbase, rowptr, dis, csr);
  k_split_w3<<<64, 256, 0, stream>>>(W1, W2, W3, Wh1, Wl1, Wh2, Wl2, Wh3, Wl3);

  const int gemm_grid = N_PAD / 64;                   // 782
  const int agg_grid  = (N_NODES * 64 + 255) / 256;   // 12500

  // ---- layer 1: 128 -> 64, relu ----
  k_gemm_mfma<D_IN, true><<<gemm_grid, 256, 0, stream>>>(x, nullptr, nullptr, Wh1, Wl1, xw);
  k_agg<0><<<agg_grid, 256, 0, stream>>>((const uint2*)xw, rowptr, csr, dis,
                                         (const float4*)b1, hhA, hlA, nullptr);
  // ---- layer 2: 64 -> 64, relu ----
  k_gemm_mfma<D_HID, false><<<gemm_grid, 256, 0, stream>>>(nullptr, hhA, hlA, Wh2, Wl2, xw);
  k_agg<0><<<agg_grid, 256, 0, stream>>>((const uint2*)xw, rowptr, csr, dis,
                                         (const float4*)b2, hhB, hlB, nullptr);
  // ---- layer 3: 64 -> 64, no activation ----
  k_gemm_mfma<D_HID, false><<<gemm_grid, 256, 0, stream>>>(nullptr, hhB, hlB, Wh3, Wl3, xw);
  k_agg<1><<<agg_grid, 256, 0, stream>>>((const uint2*)xw, rowptr, csr, dis,
                                         (const float4*)b3, nullptr, nullptr, (float4*)out);
}

// Round 7
// 139.736 us; speedup vs baseline: 2.4671x; 1.1139x over previous
//
#include <hip/hip_runtime.h>
#include <hip/hip_fp16.h>

#define N_NODES 50000
#define N_PAD   50048                 // padded rows for 64-row GEMM blocks
#define N_EDGES 800000
#define E_TOT   (N_EDGES + N_NODES)   // 850000 (self-loops inserted per node)
#define D_IN    128
#define D_HID   64

#define NB         196                // buckets of 256 nodes
#define EB_CHUNK   4096               // edges per binning block
#define BIN_BLOCKS 196                // ceil(N_EDGES / EB_CHUNK)

typedef __bf16 bf16x8 __attribute__((ext_vector_type(8)));
typedef float  f32x4  __attribute__((ext_vector_type(4)));

// ---------------- W -> MFMA-B-fragment-order bf16 hi/lo ----------------

template <int K>
__device__ __forceinline__ void pack_w(const float* __restrict__ W,
                                       __bf16* __restrict__ Bh, __bf16* __restrict__ Bl, int i) {
  constexpr int KS = K / 32;
  int j = i & 7, lane = (i >> 3) & 63, rest = i >> 9;
  int ct = rest / KS, ks = rest - ct * KS;
  int k = ks * 32 + ((lane >> 4) << 3) + j;
  int c = ct * 16 + (lane & 15);
  float v = W[k * 64 + c];
  __bf16 hb = (__bf16)v;
  Bh[i] = hb;
  Bl[i] = (__bf16)(v - (float)hb);
}

// ---------------- graph build pass A (+ fused W split): per-block bucket histogram ----------------

__global__ __launch_bounds__(256) void k_binc_sw(const int* __restrict__ dst,
                                                 unsigned* __restrict__ blkcnt,
                                                 const float* __restrict__ W1,
                                                 const float* __restrict__ W2,
                                                 const float* __restrict__ W3,
                                                 __bf16* __restrict__ Wh1, __bf16* __restrict__ Wl1,
                                                 __bf16* __restrict__ Wh2, __bf16* __restrict__ Wl2,
                                                 __bf16* __restrict__ Wh3, __bf16* __restrict__ Wl3) {
  __shared__ unsigned lh[256];
  int blk = blockIdx.x, t = threadIdx.x;
  if (blk < BIN_BLOCKS) {
    lh[t] = 0;
    __syncthreads();
    int base = blk * EB_CHUNK;
    int endv = min(base + EB_CHUNK, N_EDGES);
    for (int e = base + t; e < endv; e += 256)
      atomicAdd(&lh[((unsigned)dst[e]) >> 8], 1u);
    __syncthreads();
    blkcnt[blk * 256 + t] = lh[t];                 // plain store, no global atomics
  } else {
    int b = blk - BIN_BLOCKS;
    if (b < 32)      pack_w<D_IN >(W1, Wh1, Wl1, b * 256 + t);
    else if (b < 48) pack_w<D_HID>(W2, Wh2, Wl2, (b - 32) * 256 + t);
    else             pack_w<D_HID>(W3, Wh3, Wl3, (b - 48) * 256 + t);
  }
}

// ---------------- scan: bucket bases + per-block offsets ----------------

__global__ __launch_bounds__(256) void k_bscan(const unsigned* __restrict__ blkcnt,
                                               unsigned* __restrict__ blkoff,
                                               unsigned* __restrict__ bucket_cnt,
                                               unsigned* __restrict__ bucket_ebase,
                                               unsigned* __restrict__ bucket_cbase,
                                               unsigned* __restrict__ rowptr) {
  __shared__ unsigned se[256], sc[256];
  int t = threadIdx.x;
  unsigned run = 0;
  for (int b = 0; b < BIN_BLOCKS; b++) {           // column-wise running sum (coalesced)
    unsigned c = blkcnt[b * 256 + t];
    blkoff[b * 256 + t] = run;
    run += c;
  }
  bucket_cnt[t] = run;
  unsigned cnt   = (t < NB) ? run : 0u;
  unsigned nodes = (t < NB) ? (unsigned)min(256, N_NODES - t * 256) : 0u;
  unsigned ctot  = cnt + nodes;
  se[t] = cnt; sc[t] = ctot;
  __syncthreads();
  for (int off = 1; off < 256; off <<= 1) {
    unsigned a = (t >= off) ? se[t - off] : 0u;
    unsigned b = (t >= off) ? sc[t - off] : 0u;
    __syncthreads();
    se[t] += a; sc[t] += b;
    __syncthreads();
  }
  if (t < NB) {
    bucket_ebase[t] = se[t] - cnt;
    bucket_cbase[t] = sc[t] - ctot;
  }
  if (t == 0) rowptr[N_NODES] = E_TOT;
}

// ---------------- pass B: scatter packed edges into dense per-bucket runs ----------------

__global__ __launch_bounds__(256) void k_bins(const int* __restrict__ src,
                                              const int* __restrict__ dst,
                                              const unsigned* __restrict__ bucket_ebase,
                                              const unsigned* __restrict__ blkoff,
                                              unsigned* __restrict__ temp) {
  __shared__ unsigned lcur[256];
  int blk = blockIdx.x, t = threadIdx.x;
  lcur[t] = bucket_ebase[t] + blkoff[blk * 256 + t];
  __syncthreads();
  int base = blk * EB_CHUNK;
  int endv = min(base + EB_CHUNK, N_EDGES);
  for (int e = base + t; e < endv; e += 256) {
    unsigned d = (unsigned)dst[e];
    unsigned pos = atomicAdd(&lcur[d >> 8], 1u);
    temp[pos] = (unsigned)src[e] | ((d & 255u) << 16);   // src < 2^16, dstlocal 8b
  }
}

// ---------------- dense transform body (MFMA, split-bf16 3 products) ----------------

template <int K, bool FIRST>
__device__ __forceinline__ void gemm_body(int bid,
                                          const float* __restrict__ Xf,
                                          const __bf16* __restrict__ Ah,
                                          const __bf16* __restrict__ Al,
                                          const __bf16* __restrict__ Bh,
                                          const __bf16* __restrict__ Bl,
                                          __half* __restrict__ Y) {
  constexpr int KS = K / 32;
  const int tid  = threadIdx.x;
  const int wave = tid >> 6;
  const int lane = tid & 63;
  const int row0 = bid * 64 + wave * 16;
  const int row_a = FIRST ? min(row0 + (lane & 15), N_NODES - 1)
                          : row0 + (lane & 15);
  const int q8 = (lane >> 4) << 3;

  f32x4 acc[4];
#pragma unroll
  for (int ct = 0; ct < 4; ct++) acc[ct] = (f32x4){0.f, 0.f, 0.f, 0.f};

#pragma unroll
  for (int ks = 0; ks < KS; ks++) {
    bf16x8 ah, al;
    if (FIRST) {
      const float4* xr4 = reinterpret_cast<const float4*>(Xf + (size_t)row_a * K);
      float4 f0 = xr4[ks * 8 + (q8 >> 2) + 0];
      float4 f1 = xr4[ks * 8 + (q8 >> 2) + 1];
#pragma unroll
      for (int j = 0; j < 4; j++) {
        float a0 = (&f0.x)[j], a1 = (&f1.x)[j];
        __bf16 h0 = (__bf16)a0, h1 = (__bf16)a1;
        ah[j] = h0;     al[j] = (__bf16)(a0 - (float)h0);
        ah[4 + j] = h1; al[4 + j] = (__bf16)(a1 - (float)h1);
      }
    } else {
      size_t abase = (size_t)row_a * K + q8 + ks * 32;
      ah = *reinterpret_cast<const bf16x8*>(Ah + abase);
      al = *reinterpret_cast<const bf16x8*>(Al + abase);
    }
#pragma unroll
    for (int ct = 0; ct < 4; ct++) {
      bf16x8 bh = *reinterpret_cast<const bf16x8*>(Bh + (size_t)((ct * KS + ks) * 64 + lane) * 8);
      bf16x8 bl = *reinterpret_cast<const bf16x8*>(Bl + (size_t)((ct * KS + ks) * 64 + lane) * 8);
      acc[ct] = __builtin_amdgcn_mfma_f32_16x16x32_bf16(ah, bh, acc[ct], 0, 0, 0);
      acc[ct] = __builtin_amdgcn_mfma_f32_16x16x32_bf16(ah, bl, acc[ct], 0, 0, 0);
      acc[ct] = __builtin_amdgcn_mfma_f32_16x16x32_bf16(al, bh, acc[ct], 0, 0, 0);
    }
  }

  // C/D: col = lane&15, row = (lane>>4)*4 + reg   [m89-verified]
  const int rbase = row0 + ((lane >> 4) << 2);
  const int c     = lane & 15;
#pragma unroll
  for (int ct = 0; ct < 4; ct++)
#pragma unroll
    for (int r = 0; r < 4; r++) {
      int row = rbase + r;
      if (row < N_NODES)
        Y[(size_t)row * 64 + ct * 16 + c] = __float2half_rn(acc[ct][r]);
    }
}

// ---------------- pass C (+ fused layer-1 gemm): per-bucket CSR finalize ----------------

__global__ __launch_bounds__(256) void k_csr_gemm1(const unsigned* __restrict__ temp,
                                                   const unsigned* __restrict__ bucket_ebase,
                                                   const unsigned* __restrict__ bucket_cnt,
                                                   const unsigned* __restrict__ bucket_cbase,
                                                   unsigned* __restrict__ rowptr,
                                                   float* __restrict__ dis,
                                                   unsigned* __restrict__ csr,
                                                   const float* __restrict__ x,
                                                   const __bf16* __restrict__ Wh1,
                                                   const __bf16* __restrict__ Wl1,
                                                   __half* __restrict__ xw) {
  __shared__ unsigned hist[256], sscan[256], lfill[256];
  if (blockIdx.x >= NB) {                 // gemm role (independent of CSR)
    gemm_body<D_IN, true>(blockIdx.x - NB, x, nullptr, nullptr, Wh1, Wl1, xw);
    return;
  }
  int b = blockIdx.x, t = threadIdx.x;
  unsigned ebase = bucket_ebase[b], ecnt = bucket_cnt[b], cbase = bucket_cbase[b];
  int nodes = min(256, N_NODES - b * 256);
  hist[t] = 0;
  __syncthreads();
  for (unsigned i = t; i < ecnt; i += 256)
    atomicAdd(&hist[(temp[ebase + i] >> 16) & 255u], 1u);
  __syncthreads();
  unsigned deg = (t < nodes) ? hist[t] + 1u : 0u;        // + self-loop
  sscan[t] = deg;
  __syncthreads();
  for (int off = 1; off < 256; off <<= 1) {
    unsigned v = (t >= off) ? sscan[t - off] : 0u;
    __syncthreads();
    sscan[t] += v;
    __syncthreads();
  }
  unsigned excl = sscan[t] - deg;
  if (t < nodes) {
    int node = b * 256 + t;
    rowptr[node] = cbase + excl;
    dis[node] = rsqrtf((float)deg);
    csr[cbase + excl] = (unsigned)node;                  // self-loop entry
  }
  lfill[t] = excl + 1u;
  __syncthreads();
  for (unsigned i = t; i < ecnt; i += 256) {
    unsigned v = temp[ebase + i];
    unsigned d = (v >> 16) & 255u;
    unsigned pos = atomicAdd(&lfill[d], 1u);
    csr[cbase + pos] = v & 0xFFFFu;
  }
}

// ---------------- layer 2/3 gemm wrappers ----------------

__global__ __launch_bounds__(256) void k_gemm23(const __bf16* __restrict__ Ah,
                                                const __bf16* __restrict__ Al,
                                                const __bf16* __restrict__ Bh,
                                                const __bf16* __restrict__ Bl,
                                                __half* __restrict__ Y) {
  gemm_body<D_HID, false>(blockIdx.x, nullptr, Ah, Al, Bh, Bl, Y);
}

// ---------------- aggregate: OUT[i][:] = relu?( sum_e nrm*XW[src][:] + b ) ----------------
// Wave-per-node. lane = grp(=lane>>3, edge slot 0..7) x sub(=lane&7, 8-half group).
// 16 edges in flight per iter via two float4 (16B fp16) gathers; 2nd guarded (wave-uniform).

template <int MODE>
__global__ __launch_bounds__(256) void k_agg(const float4* __restrict__ XW4,
                                             const unsigned* __restrict__ rowptr,
                                             const unsigned* __restrict__ csr,
                                             const float* __restrict__ dis,
                                             const float4* __restrict__ bias4,
                                             __bf16* __restrict__ hh,
                                             __bf16* __restrict__ hl,
                                             float4* __restrict__ OUT4) {
  int node = (int)((blockIdx.x * blockDim.x + threadIdx.x) >> 6);
  int lane = threadIdx.x & 63;
  if (node >= N_NODES) return;
  const int sub = lane & 7;       // halves sub*8 .. sub*8+7
  const int grp = lane >> 3;      // edge slot

  const float disd = dis[node];
  unsigned beg = rowptr[node], end = rowptr[node + 1];
  float acc0[8] = {0,0,0,0,0,0,0,0};
  float acc1[8] = {0,0,0,0,0,0,0,0};

  for (unsigned j = beg; j < end; j += 64) {
    int nj = (int)min(64u, end - j);
    unsigned s = 0u; float nrm = 0.f;
    if (lane < nj) {
      s = csr[j + lane];
      nrm = dis[s] * disd;
    }
    for (int k = 0; k < nj; k += 16) {
      int e0 = k + grp;
      unsigned s0 = (unsigned)__shfl((int)s, e0);
      float    n0 = __shfl(nrm, e0);
      float4 v0 = XW4[(size_t)s0 * 8 + sub];           // 16B = 8 fp16
      const __half2* h0 = reinterpret_cast<const __half2*>(&v0);
#pragma unroll
      for (int q = 0; q < 4; q++) {
        float2 f = __half22float2(h0[q]);
        acc0[2*q]   += n0 * f.x;
        acc0[2*q+1] += n0 * f.y;
      }
      if (k + 8 < nj) {                                 // wave-uniform guard
        int e1 = k + grp + 8;
        unsigned s1 = (unsigned)__shfl((int)s, e1);
        float    n1 = __shfl(nrm, e1);
        float4 v1 = XW4[(size_t)s1 * 8 + sub];
        const __half2* h1 = reinterpret_cast<const __half2*>(&v1);
#pragma unroll
        for (int q = 0; q < 4; q++) {
          float2 f = __half22float2(h1[q]);
          acc1[2*q]   += n1 * f.x;
          acc1[2*q+1] += n1 * f.y;
        }
      }
    }
  }

  float acc[8];
#pragma unroll
  for (int i = 0; i < 8; i++) acc[i] = acc0[i] + acc1[i];
  // fold edge-slot partials: grp lives in lane bits 3,4,5
#pragma unroll
  for (int i = 0; i < 8; i++) {
    acc[i] += __shfl_xor(acc[i], 8);
    acc[i] += __shfl_xor(acc[i], 16);
    acc[i] += __shfl_xor(acc[i], 32);
  }

  if (grp == 0) {
    float4 ba = bias4[sub * 2], bb = bias4[sub * 2 + 1];
    acc[0] += ba.x; acc[1] += ba.y; acc[2] += ba.z; acc[3] += ba.w;
    acc[4] += bb.x; acc[5] += bb.y; acc[6] += bb.z; acc[7] += bb.w;
    if (MODE == 0) {
      bf16x8 hv, lv;
#pragma unroll
      for (int i = 0; i < 8; i++) {
        float f = fmaxf(acc[i], 0.f);
        __bf16 hb = (__bf16)f;
        hv[i] = hb;
        lv[i] = (__bf16)(f - (float)hb);
      }
      *reinterpret_cast<bf16x8*>(&hh[(size_t)node * 64 + sub * 8]) = hv;
      *reinterpret_cast<bf16x8*>(&hl[(size_t)node * 64 + sub * 8]) = lv;
    } else {
      float4 o0 = {acc[0], acc[1], acc[2], acc[3]};
      float4 o1 = {acc[4], acc[5], acc[6], acc[7]};
      OUT4[(size_t)node * 16 + sub * 2]     = o0;
      OUT4[(size_t)node * 16 + sub * 2 + 1] = o1;
    }
  }
}

// ---------------- launch ----------------

extern "C" void kernel_launch(void* const* d_in, const int* in_sizes, int n_in,
                              void* d_out, int out_size, void* d_ws, size_t ws_size,
                              hipStream_t stream) {
  const float* x    = (const float*)d_in[0];
  const int*   eidx = (const int*)d_in[1];      // [2][800000], int32
  const float* W1   = (const float*)d_in[2];
  const float* b1   = (const float*)d_in[3];
  const float* W2   = (const float*)d_in[4];
  const float* b2   = (const float*)d_in[5];
  const float* W3   = (const float*)d_in[6];
  const float* b3   = (const float*)d_in[7];
  float* out = (float*)d_out;

  const int* e_src = eidx;
  const int* e_dst = eidx + N_EDGES;

  size_t off = 0;
  auto alloc = [&](size_t bytes) -> void* {
    void* p = (char*)d_ws + off;
    off += (bytes + 255) & ~(size_t)255;
    return p;
  };
  unsigned* rowptr  = (unsigned*)alloc((size_t)(N_NODES + 1) * 4);
  float*    dis     = (float*)alloc((size_t)N_NODES * 4);
  unsigned* csr     = (unsigned*)alloc((size_t)E_TOT * 4);
  unsigned* temp    = (unsigned*)alloc((size_t)N_EDGES * 4);
  unsigned* blkcnt  = (unsigned*)alloc((size_t)BIN_BLOCKS * 256 * 4);
  unsigned* blkoff  = (unsigned*)alloc((size_t)BIN_BLOCKS * 256 * 4);
  unsigned* bcnt    = (unsigned*)alloc(256 * 4);
  unsigned* bebase  = (unsigned*)alloc(256 * 4);
  unsigned* bcbase  = (unsigned*)alloc(256 * 4);
  __half*   xw      = (__half*)alloc((size_t)N_PAD * 64 * 2);
  __bf16*   hhA     = (__bf16*)alloc((size_t)N_PAD * 64 * 2);
  __bf16*   hlA     = (__bf16*)alloc((size_t)N_PAD * 64 * 2);
  __bf16*   hhB     = (__bf16*)alloc((size_t)N_PAD * 64 * 2);
  __bf16*   hlB     = (__bf16*)alloc((size_t)N_PAD * 64 * 2);
  __bf16*   Wh1     = (__bf16*)alloc((size_t)D_IN * 64 * 2);
  __bf16*   Wl1     = (__bf16*)alloc((size_t)D_IN * 64 * 2);
  __bf16*   Wh2     = (__bf16*)alloc((size_t)D_HID * 64 * 2);
  __bf16*   Wl2     = (__bf16*)alloc((size_t)D_HID * 64 * 2);
  __bf16*   Wh3     = (__bf16*)alloc((size_t)D_HID * 64 * 2);
  __bf16*   Wl3     = (__bf16*)alloc((size_t)D_HID * 64 * 2);

  const int gemm_grid = N_PAD / 64;                   // 782
  const int agg_grid  = (N_NODES * 64 + 255) / 256;   // 12500

  // ---- graph build + W split + layer-1 gemm (fused where independent) ----
  k_binc_sw<<<BIN_BLOCKS + 64, 256, 0, stream>>>(e_dst, blkcnt, W1, W2, W3,
                                                 Wh1, Wl1, Wh2, Wl2, Wh3, Wl3);
  k_bscan<<<1, 256, 0, stream>>>(blkcnt, blkoff, bcnt, bebase, bcbase, rowptr);
  k_bins<<<BIN_BLOCKS, 256, 0, stream>>>(e_src, e_dst, bebase, blkoff, temp);
  k_csr_gemm1<<<NB + gemm_grid, 256, 0, stream>>>(temp, bebase, bcnt, bcbase,
                                                  rowptr, dis, csr, x, Wh1, Wl1, xw);
  // ---- layer 1 aggregate ----
  k_agg<0><<<agg_grid, 256, 0, stream>>>((const float4*)xw, rowptr, csr, dis,
                                         (const float4*)b1, hhA, hlA, nullptr);
  // ---- layer 2 ----
  k_gemm23<<<gemm_grid, 256, 0, stream>>>(hhA, hlA, Wh2, Wl2, xw);
  k_agg<0><<<agg_grid, 256, 0, stream>>>((const float4*)xw, rowptr, csr, dis,
                                         (const float4*)b2, hhB, hlB, nullptr);
  // ---- layer 3 ----
  k_gemm23<<<gemm_grid, 256, 0, stream>>>(hhB, hlB, Wh3, Wl3, xw);
  k_agg<1><<<agg_grid, 256, 0, stream>>>((const float4*)xw, rowptr, csr, dis,
                                         (const float4*)b3, nullptr, nullptr, (float4*)out);
}